// Round 22
// baseline (1717.738 us; speedup 1.0000x reference)
//
#include <hip/hip_runtime.h>
#include <cstdint>
#include <cstddef>

#define TSTEPS 100
#define NB 256
#define INF 2312
#define HIDN 512
#define NOUT 10
#define NTILES 1600               // (25600/128) x (512/64)

// ws layout (float offsets) — as R20/R21; ctr[0]=tile queue, ctr[1023]=mode
#define OFF_WT  0                 // 262144 floats (w_rec transposed, 1 MB)
#define OFF_ZB  262144            // 65536 floats = [2][256][512] u8 z-transit
#define OFF_CTR 327680            // 1024 u32; [0]=queue, [1023]=mode
#define OFF_CI  328704            // 13107200 floats (input-projection cache)
#define WS_FLOATS 13435904        // 53.7 MB

typedef double f64x4 __attribute__((ext_vector_type(4)));

// D-layout candidates for mfma_f64_16x16x4: lane l, reg r -> (row m, col n)
__device__ __forceinline__ void dpos_f64(int di, int lane, int r, int& m, int& n) {
    const int l16 = lane & 15, kq = lane >> 4;
    switch (di) {
    case 0:  m = 4 * kq + r;         n = l16;                break;
    case 1:  m = l16;                n = 4 * kq + r;         break;
    case 2:  m = kq + 4 * r;         n = l16;                break;
    case 3:  m = l16;                n = kq + 4 * r;         break;
    case 4:  m = lane >> 2;          n = 4 * (lane & 3) + r; break;
    default: n = lane >> 2;          m = 4 * (lane & 3) + r; break;
    }
}

// build w_recT[j][h] = w_rec[h][j]; zero z-transit + counters (incl. queue) + mode
__global__ __launch_bounds__(256) void init_kernel(float* __restrict__ ws,
                                                   const float* __restrict__ w_rec) {
    int n = blockIdx.x * 256 + threadIdx.x;
    if (n < HIDN * HIDN) {
        int j = n >> 9, h = n & 511;
        ws[n] = w_rec[h * HIDN + j];
    } else if (n < OFF_CI) {
        ws[n] = 0.0f;
    }
}

// Exact-integer layout decoder (VERBATIM R14; HW-verified R14/R16/R19-R21).
__global__ __launch_bounds__(64) void probe_kernel(unsigned int* __restrict__ mode_out) {
    const int l = threadIdx.x;
    __shared__ unsigned int maskls;
    if (l == 0) maskls = 0xFFFFFFu;
    __syncthreads();
    double a1v = 1.0 + 3.0 * (double)l, b1v = 2.0 + 5.0 * (double)l;
    double a2v = 7.0 - 2.0 * (double)l, b2v = -3.0 + (double)l;
    f64x4 pacc;
#pragma unroll
    for (int r = 0; r < 4; ++r) pacc[r] = 1000.0 * r + 17.0 * l;
    pacc = __builtin_amdgcn_mfma_f64_16x16x4f64(a1v, b1v, pacc, 0, 0, 0);
    pacc = __builtin_amdgcn_mfma_f64_16x16x4f64(a2v, b2v, pacc, 0, 0, 0);
    unsigned int my = 0;
    for (int ai = 0; ai < 2; ++ai)
        for (int bi = 0; bi < 2; ++bi)
            for (int di = 0; di < 6; ++di) {
                bool ok = true;
                for (int r = 0; r < 4; ++r) {
                    int m, n; dpos_f64(di, l, r, m, n);
                    double e = 1000.0 * r + 17.0 * l;
                    for (int k = 0; k < 4; ++k) {
                        int lA = ai ? (4 * m + k) : (m + 16 * k);
                        int lB = bi ? (4 * n + k) : (n + 16 * k);
                        e += (1.0 + 3.0 * (double)lA) * (2.0 + 5.0 * (double)lB)
                           + (7.0 - 2.0 * (double)lA) * (-3.0 + (double)lB);
                    }
                    ok = ok && (pacc[r] == e);
                }
                if (ok) my |= 1u << (ai * 12 + bi * 6 + di);
            }
    atomicAnd(&maskls, my);
    __syncthreads();
    if (l == 0) mode_out[0] = maskls ? (unsigned)(__ffs((int)maskls) - 1) : 255u;
}

// MFMA f64 GEMM v6: 128x64 tile — LDS-read:MFMA ratio 0.75 (was 1.125).
// Wave = 2 m-tiles x 4 n-tiles (acc[8], 64 VGPR): per s-iter 2 A + 4 B reads
// feed 8 MFMAs. LDS 26.6 KB -> 3 blocks/CU (12 waves): LDS-BW 144cyc < MFMA
// 192cyc -> MFMA-bound (prior configs were LDS-bound at 144 vs 128).
// Per-element MFMA k-sequence IDENTICAL to R14/R16/R20/R21 (s ascending,
// k0 ascending, same operands) -> bit-identical ci (fingerprint).
__global__ __launch_bounds__(256, 3) void gemm_mfma6(const float* __restrict__ X,
        const float* __restrict__ Win, float* __restrict__ C,
        const unsigned int* __restrict__ modep, unsigned int* __restrict__ q) {
    const unsigned int mode = modep[0];
    if (mode >= 24u) return;
    const int di = (int)(mode % 6u), bi = (int)((mode / 6u) & 1u), ai = (int)(mode / 12u);
    __shared__ float As[32][136];    // [k][row 0..127], 17.4 KB, stride==8 mod 32
    __shared__ float Bs[32][72];     // [k][col 0..63],  9.2 KB, stride==8 mod 32
    __shared__ unsigned int tilej;
    const int tid = threadIdx.x;
    const int lane = tid & 63, wv = tid >> 6;
    const int a_m = ai ? (lane >> 2) : (lane & 15);
    const int a_k = ai ? (lane & 3) : (lane >> 4);
    const int b_n = bi ? (lane >> 2) : (lane & 15);
    const int b_k = bi ? (lane & 3) : (lane >> 4);
    const int sra = tid >> 1, ska = (tid & 1) * 16;   // A staging: 16 floats/thr
    const int srb = tid >> 2, skb = (tid & 3) * 8;    // B staging: 8 floats/thr

    for (;;) {
        if (tid == 0) tilej = atomicAdd(q, 1u);
        __syncthreads();                 // broadcast tilej; fences LDS reuse
        const unsigned int j = tilej;
        if (j >= NTILES) break;
        const int row0 = (int)(j >> 3) * 128, col0 = (int)(j & 7) * 64;

        float4 va[4], vb[2];
#pragma unroll
        for (int qq = 0; qq < 4; ++qq)
            va[qq] = *(const float4*)(X + (size_t)(row0 + sra) * INF + ska + qq * 4);
#pragma unroll
        for (int qq = 0; qq < 2; ++qq)
            vb[qq] = *(const float4*)(Win + (size_t)(col0 + srb) * INF + skb + qq * 4);

        f64x4 acc[8] = {};   // [mt*4+nt]
        for (int k0 = 0; k0 < INF; k0 += 32) {
            __syncthreads();
#pragma unroll
            for (int qq = 0; qq < 4; ++qq) {
                int kc = ska + qq * 4;
                As[kc + 0][sra] = va[qq].x; As[kc + 1][sra] = va[qq].y;
                As[kc + 2][sra] = va[qq].z; As[kc + 3][sra] = va[qq].w;
            }
#pragma unroll
            for (int qq = 0; qq < 2; ++qq) {
                int kc = skb + qq * 4;
                Bs[kc + 0][srb] = vb[qq].x; Bs[kc + 1][srb] = vb[qq].y;
                Bs[kc + 2][srb] = vb[qq].z; Bs[kc + 3][srb] = vb[qq].w;
            }
            __syncthreads();
            const int kn = k0 + 32;
            if (kn < INF) {
#pragma unroll
                for (int qq = 0; qq < 4; ++qq) {
                    int gk = kn + ska + qq * 4;
                    float4 a = make_float4(0.f, 0.f, 0.f, 0.f);
                    if (gk < INF)   // INF%4==0 -> full float4 in-bounds
                        a = *(const float4*)(X + (size_t)(row0 + sra) * INF + gk);
                    va[qq] = a;
                }
#pragma unroll
                for (int qq = 0; qq < 2; ++qq) {
                    int gk = kn + skb + qq * 4;
                    float4 b = make_float4(0.f, 0.f, 0.f, 0.f);
                    if (gk < INF)
                        b = *(const float4*)(Win + (size_t)(col0 + srb) * INF + gk);
                    vb[qq] = b;
                }
            }
#pragma unroll
            for (int s = 0; s < 8; ++s) {
                double a0 = (double)As[s * 4 + a_k][wv * 32 + a_m];
                double a1 = (double)As[s * 4 + a_k][wv * 32 + 16 + a_m];
#pragma unroll
                for (int nt = 0; nt < 4; ++nt) {
                    double b = (double)Bs[s * 4 + b_k][nt * 16 + b_n];
                    acc[nt]     = __builtin_amdgcn_mfma_f64_16x16x4f64(a0, b, acc[nt], 0, 0, 0);
                    acc[4 + nt] = __builtin_amdgcn_mfma_f64_16x16x4f64(a1, b, acc[4 + nt], 0, 0, 0);
                }
            }
        }
#pragma unroll
        for (int mt = 0; mt < 2; ++mt)
#pragma unroll
            for (int nt = 0; nt < 4; ++nt)
#pragma unroll
                for (int r = 0; r < 4; ++r) {
                    int m, n; dpos_f64(di, lane, r, m, n);
                    C[(size_t)(row0 + wv * 32 + mt * 16 + m) * HIDN + col0 + nt * 16 + n]
                        = (float)acc[mt * 4 + nt][r];
                }
    }
}

// Vector GEMM fallback: VERBATIM R10 (frozen chain). Runs only if mode==255.
__global__ __launch_bounds__(256, 2) void gemm_vec(const float* __restrict__ X,
        const float* __restrict__ Win, float* __restrict__ C,
        const unsigned int* __restrict__ modep) {
    if (modep[0] < 24u) return;
    __shared__ double As[32][130];
    __shared__ double Bs[32][144];
    const int tid = threadIdx.x;
    const int tx = tid & 15;
    const int ty = tid >> 4;
    const int row0 = blockIdx.y * 128, col0 = blockIdx.x * 128;
    const int sr = tid >> 1, sk = (tid & 1) * 16;
    const int srz = sr + (sr >> 3);
    float4 va[4], vb[4];
#pragma unroll
    for (int q = 0; q < 4; ++q) {
        int gk = sk + q * 4;
        va[q] = *(const float4*)(X + (size_t)(row0 + sr) * INF + gk);
        vb[q] = *(const float4*)(Win + (size_t)(col0 + sr) * INF + gk);
    }
    double acc[8][8] = {};
    for (int k0 = 0; k0 < INF; k0 += 32) {
        __syncthreads();
#pragma unroll
        for (int q = 0; q < 4; ++q) {
            int kc = sk + q * 4;
            As[kc + 0][sr] = (double)va[q].x; As[kc + 1][sr] = (double)va[q].y;
            As[kc + 2][sr] = (double)va[q].z; As[kc + 3][sr] = (double)va[q].w;
            Bs[kc + 0][srz] = (double)vb[q].x; Bs[kc + 1][srz] = (double)vb[q].y;
            Bs[kc + 2][srz] = (double)vb[q].z; Bs[kc + 3][srz] = (double)vb[q].w;
        }
        __syncthreads();
        const int kn = k0 + 32;
        if (kn < INF) {
#pragma unroll
            for (int q = 0; q < 4; ++q) {
                int gk = kn + sk + q * 4;
                float4 a = make_float4(0.f, 0.f, 0.f, 0.f);
                float4 b = make_float4(0.f, 0.f, 0.f, 0.f);
                if (gk < INF) {
                    a = *(const float4*)(X + (size_t)(row0 + sr) * INF + gk);
                    b = *(const float4*)(Win + (size_t)(col0 + sr) * INF + gk);
                }
                va[q] = a; vb[q] = b;
            }
        }
#pragma unroll 4
        for (int kk = 0; kk < 32; ++kk) {
            double ad[8], bd[8];
#pragma unroll
            for (int i = 0; i < 8; ++i) ad[i] = As[kk][ty * 8 + i];
#pragma unroll
            for (int j = 0; j < 8; ++j) bd[j] = Bs[kk][9 * tx + j];
#pragma unroll
            for (int i = 0; i < 8; ++i)
#pragma unroll
                for (int j = 0; j < 8; ++j)
                    acc[i][j] += ad[i] * bd[j];
        }
    }
#pragma unroll
    for (int i = 0; i < 8; ++i) {
#pragma unroll
        for (int jj = 0; jj < 2; ++jj) {
            float4 o;
            o.x = (float)acc[i][jj * 4 + 0]; o.y = (float)acc[i][jj * 4 + 1];
            o.z = (float)acc[i][jj * 4 + 2]; o.w = (float)acc[i][jj * 4 + 3];
            *(float4*)(C + (size_t)(row0 + ty * 8 + i) * HIDN + col0 + tx * 8 + jj * 4) = o;
        }
    }
}

// Fused stepper with TAG-EMBEDDED z exchange. VERBATIM R19/R20/R21 (~250us).
__global__ __launch_bounds__(512) void fused_tag(const float* __restrict__ ci,
        const float* __restrict__ wT, const float* __restrict__ w_out,
        float* __restrict__ out, unsigned char* __restrict__ zb) {
    __shared__ float zfb[4096];        // 16 KB union: zf[b][j] | fbufT[c2][b][h]
    __shared__ float wout2[2][512];    // 4 KB
    const int tid = threadIdx.x;
    const int wv = tid >> 6, lane = tid & 63;
    const int i = (int)blockIdx.x;
    const int c = (i >> 3) & 7;                    // h-chunk / group member
    const int g = (i & 7) | ((i >> 6) << 3);       // group 0..31 (co-XCD)
    const int b0 = g * 8;

    float wreg[64];
#pragma unroll
    for (int qq = 0; qq < 64; ++qq)
        wreg[qq] = wT[(size_t)((wv << 6) + qq) * HIDN + (c << 6) + lane];

    if (tid < 512) {
        wout2[0][tid] = w_out[c * HIDN + tid];
        wout2[1][tid] = (c < 2) ? w_out[(8 + c) * HIDN + tid] : 0.0f;
    }
    for (int idx = tid; idx < 4096; idx += 512) zfb[idx] = 0.0f;  // z_{-1}=0
    __syncthreads();

    unsigned char* zbA = zb + (size_t)b0 * HIDN;            // [b][j] u8
    unsigned char* zbB = zb + 131072 + (size_t)b0 * HIDN;

    float pos = 0.0f;                  // fold phase: thread = (batch wv, h lane)
    float vA = 0.f, iA = 0.f, vB = 0.f, iB = 0.f;   // LI state on lane 0

    for (int t = 0; t < TSTEPS; ++t) {
        // ---- gather (frozen fmac chains, verbatim R9) ----
        float f[8] = {0.f, 0.f, 0.f, 0.f, 0.f, 0.f, 0.f, 0.f};
#pragma unroll
        for (int q4 = 0; q4 < 16; ++q4) {
            float4 z4[8];
#pragma unroll
            for (int b = 0; b < 8; ++b)
                z4[b] = *(const float4*)&zfb[b * 512 + (wv << 6) + q4 * 4];
#pragma unroll
            for (int b = 0; b < 8; ++b) {
                f[b] = __fmaf_rn(z4[b].x, wreg[q4 * 4 + 0], f[b]);
                f[b] = __fmaf_rn(z4[b].y, wreg[q4 * 4 + 1], f[b]);
                f[b] = __fmaf_rn(z4[b].z, wreg[q4 * 4 + 2], f[b]);
                f[b] = __fmaf_rn(z4[b].w, wreg[q4 * 4 + 3], f[b]);
            }
        }
        __syncthreads();   // B1: all zf reads done; region becomes fbufT
#pragma unroll
        for (int b = 0; b < 8; ++b)
            zfb[((wv << 3) + b) * 64 + lane] = f[b];   // fbufT[c2=wv][b][h]
        __syncthreads();   // B2: partials published

        // ---- fold + neuron update (frozen) + tagged z publish ----
        double acc = 0.0;
#pragma unroll
        for (int c2 = 0; c2 < 8; ++c2)
            acc += (double)zfb[((c2 << 3) + wv) * 64 + lane];
        float rec32 = (float)acc;
        float civ = ci[((size_t)t * NB + (b0 + wv)) * HIDN + (c << 6) + lane];
        float cur = __fadd_rn(__fadd_rn(civ, rec32), 1e-4f);   // (in+rec)+I_APP
        float mc = __fmul_rn(2.5e5f, cur);                     // MU*cur
        pos = __fadd_rn(pos, __fmul_rn(1e-10f, mc));           // pos += DT*(..)
        bool zbit = __fsub_rn(pos, 2.5e-8f) > 0.0f;            // pos-W2 > 0
        pos = zbit ? 0.0f : pos;
        unsigned char* zw = (t & 1) ? zbB : zbA;
        const unsigned int tag2 = ((unsigned)(t >> 1) + 1u) << 1;   // <=101
        __hip_atomic_store(&zw[wv * HIDN + (c << 6) + lane],
                           (unsigned char)(tag2 | (zbit ? 1u : 0u)),
                           __ATOMIC_RELAXED, __HIP_MEMORY_SCOPE_AGENT);
        __syncthreads();   // B3: fbufT reads done -> zfb reusable as zf

        // ---- pull z_t: poll tagged bytes (data == flag) ----
        {
            const int bb = tid >> 6, j8 = (tid & 63) * 8;
            const unsigned char* zr = zw + bb * HIDN + j8;
            const unsigned int t2b = tag2 * 0x01010101u;
            unsigned int vx, vy;
            for (;;) {
                vx = __hip_atomic_load((const unsigned int*)zr,
                                       __ATOMIC_RELAXED, __HIP_MEMORY_SCOPE_AGENT);
                vy = __hip_atomic_load((const unsigned int*)(zr + 4),
                                       __ATOMIC_RELAXED, __HIP_MEMORY_SCOPE_AGENT);
                if (((vx & 0xFEFEFEFEu) == t2b) && ((vy & 0xFEFEFEFEu) == t2b))
                    break;
                __builtin_amdgcn_s_sleep(1);
            }
            float4 o0, o1;
            o0.x = (float)(vx & 1u);         o0.y = (float)((vx >> 8) & 1u);
            o0.z = (float)((vx >> 16) & 1u); o0.w = (float)((vx >> 24) & 1u);
            o1.x = (float)(vy & 1u);         o1.y = (float)((vy >> 8) & 1u);
            o1.z = (float)((vy >> 16) & 1u); o1.w = (float)((vy >> 24) & 1u);
            *(float4*)&zfb[bb * 512 + j8] = o0;
            *(float4*)&zfb[bb * 512 + j8 + 4] = o1;
        }
        __syncthreads();   // B4: zf ready for LI + next gather

        // ---- LI readout for step t (frozen chain; wave = batch wv) ----
#pragma unroll
        for (int oo = 0; oo < 2; ++oo) {
            int o = (oo == 0) ? c : (c < 2 ? 8 + c : -1);
            if (o < 0) continue;
            double part = 0.0;
#pragma unroll
            for (int c2 = 0; c2 < 8; ++c2) {
                double zfv = (double)zfb[wv * 512 + (c2 << 6) + lane];
                part = __fma_rn(zfv, (double)wout2[oo][(c2 << 6) + lane], part);
            }
#pragma unroll
            for (int off = 32; off > 0; off >>= 1) part += __shfl_down(part, off);
            if (lane == 0) {
                float inp = (float)part;
                float vvv = (oo == 0) ? vA : vB;
                float iiv = (oo == 0) ? iA : iB;
                float vn = __fadd_rn(vvv, __fmul_rn(1e-8f, __fsub_rn(iiv, vvv)));
                float t2 = __fmul_rn(2e-8f, iiv);
                float in2 = __fadd_rn(__fsub_rn(iiv, t2), inp);
                if (oo == 0) { vA = vn; iA = in2; } else { vB = vn; iB = in2; }
                out[((size_t)t * NB + (b0 + wv)) * NOUT + o] = vn;
            }
        }
    }
}

extern "C" void kernel_launch(void* const* d_in, const int* in_sizes, int n_in,
                              void* d_out, int out_size, void* d_ws, size_t ws_size,
                              hipStream_t stream) {
    (void)in_sizes; (void)n_in; (void)out_size;
    const float* x     = (const float*)d_in[0];
    const float* w_in  = (const float*)d_in[1];
    const float* w_rec = (const float*)d_in[2];
    const float* w_out = (const float*)d_in[3];
    float* out = (float*)d_out;
    float* ws  = (float*)d_ws;
    if (ws_size < (size_t)WS_FLOATS * 4) return;

    float* wT = ws + OFF_WT;
    unsigned char* zb = (unsigned char*)(ws + OFF_ZB);
    unsigned int* ctr = (unsigned int*)(ws + OFF_CTR);
    unsigned int* queue = ctr;         // [0], zeroed by init each launch
    unsigned int* mode = ctr + 1023;
    float* ci = ws + OFF_CI;

    hipLaunchKernelGGL(init_kernel, dim3((OFF_CI + 255) / 256), dim3(256), 0,
                       stream, ws, w_rec);
    hipLaunchKernelGGL(probe_kernel, dim3(1), dim3(64), 0, stream, mode);
    hipLaunchKernelGGL(gemm_mfma6, dim3(768), dim3(256), 0, stream,
                       x, w_in, ci, mode, queue);
    hipLaunchKernelGGL(gemm_vec, dim3(4, 200), dim3(256), 0, stream,
                       x, w_in, ci, mode);
    hipLaunchKernelGGL(fused_tag, dim3(NB), dim3(512), 0, stream,
                       ci, wT, w_out, out, zb);
}

// Round 23
// 1135.605 us; speedup vs baseline: 1.5126x; 1.5126x over previous
//
#include <hip/hip_runtime.h>
#include <cstdint>
#include <cstddef>

#define TSTEPS 100
#define NB 256
#define INF 2312
#define HIDN 512
#define NOUT 10
#define BKT 73                    // ceil(2312/32) K-tiles for bf16 path

// ws layout (float offsets); ctr[1022]=bf16 mode, ctr[1023]=f64 mode
#define OFF_WT  0                 // 262144 floats (w_rec transposed, 1 MB)
#define OFF_ZB  262144            // 65536 floats = [2][256][512] u8 z-transit
#define OFF_CTR 327680            // 1024 u32
#define OFF_CI  328704            // 13107200 floats (input-projection cache)
#define WS_FLOATS 13435904        // 53.7 MB

typedef double f64x4 __attribute__((ext_vector_type(4)));
typedef float  f32x4 __attribute__((ext_vector_type(4)));
typedef short  short8 __attribute__((ext_vector_type(8)));

// ---------- f64 MFMA D-layout candidates (R14, HW-verified) ----------
__device__ __forceinline__ void dpos_f64(int di, int lane, int r, int& m, int& n) {
    const int l16 = lane & 15, kq = lane >> 4;
    switch (di) {
    case 0:  m = 4 * kq + r;         n = l16;                break;
    case 1:  m = l16;                n = 4 * kq + r;         break;
    case 2:  m = kq + 4 * r;         n = l16;                break;
    case 3:  m = l16;                n = kq + 4 * r;         break;
    case 4:  m = lane >> 2;          n = 4 * (lane & 3) + r; break;
    default: n = lane >> 2;          m = 4 * (lane & 3) + r; break;
    }
}

// exact truncation 3-way bf16 split: x == b1+b2+b3 bit-exactly
__device__ __forceinline__ void bsplit(float x, unsigned short& h1,
                                       unsigned short& h2, unsigned short& h3) {
    unsigned int xb = __float_as_uint(x);
    h1 = (unsigned short)(xb >> 16);
    float r1 = x - __uint_as_float(xb & 0xFFFF0000u);     // exact (Sterbenz)
    unsigned int r1b = __float_as_uint(r1);
    h2 = (unsigned short)(r1b >> 16);
    float r2 = r1 - __uint_as_float(r1b & 0xFFFF0000u);   // exact
    h3 = (unsigned short)(__float_as_uint(r2) >> 16);
}

// build w_recT[j][h] = w_rec[h][j]; zero z-transit + counters + mode slots
__global__ __launch_bounds__(256) void init_kernel(float* __restrict__ ws,
                                                   const float* __restrict__ w_rec) {
    int n = blockIdx.x * 256 + threadIdx.x;
    if (n < HIDN * HIDN) {
        int j = n >> 9, h = n & 511;
        ws[n] = w_rec[h * HIDN + j];
    } else if (n < OFF_CI) {
        ws[n] = 0.0f;
    }
}

// f64 layout decoder (VERBATIM R14; HW-verified R14/R16/R19-R22)
__global__ __launch_bounds__(64) void probe_kernel(unsigned int* __restrict__ mode_out) {
    const int l = threadIdx.x;
    __shared__ unsigned int maskls;
    if (l == 0) maskls = 0xFFFFFFu;
    __syncthreads();
    double a1v = 1.0 + 3.0 * (double)l, b1v = 2.0 + 5.0 * (double)l;
    double a2v = 7.0 - 2.0 * (double)l, b2v = -3.0 + (double)l;
    f64x4 pacc;
#pragma unroll
    for (int r = 0; r < 4; ++r) pacc[r] = 1000.0 * r + 17.0 * l;
    pacc = __builtin_amdgcn_mfma_f64_16x16x4f64(a1v, b1v, pacc, 0, 0, 0);
    pacc = __builtin_amdgcn_mfma_f64_16x16x4f64(a2v, b2v, pacc, 0, 0, 0);
    unsigned int my = 0;
    for (int ai = 0; ai < 2; ++ai)
        for (int bi = 0; bi < 2; ++bi)
            for (int di = 0; di < 6; ++di) {
                bool ok = true;
                for (int r = 0; r < 4; ++r) {
                    int m, n; dpos_f64(di, l, r, m, n);
                    double e = 1000.0 * r + 17.0 * l;
                    for (int k = 0; k < 4; ++k) {
                        int lA = ai ? (4 * m + k) : (m + 16 * k);
                        int lB = bi ? (4 * n + k) : (n + 16 * k);
                        e += (1.0 + 3.0 * (double)lA) * (2.0 + 5.0 * (double)lB)
                           + (7.0 - 2.0 * (double)lA) * (-3.0 + (double)lB);
                    }
                    ok = ok && (pacc[r] == e);
                }
                if (ok) my |= 1u << (ai * 12 + bi * 6 + di);
            }
    atomicAnd(&maskls, my);
    __syncthreads();
    if (l == 0) mode_out[0] = maskls ? (unsigned)(__ffs((int)maskls) - 1) : 255u;
}

// bf16 16x16x32 layout decoder: exact-integer probe over 8 supported combos
// (A,B feed: standard / quad-row; D: normal / transposed). All probe values
// are bf16-exact ints; sums < 2^24 -> exact fp32 -> equality check is rigorous.
__global__ __launch_bounds__(64) void probe_bf(unsigned int* __restrict__ out) {
    const int l = threadIdx.x;
    __shared__ unsigned int maskls;
    if (l == 0) maskls = 0xFFu;
    __syncthreads();
    short8 a1v, a2v, b1v, b2v;
#pragma unroll
    for (int j = 0; j < 8; ++j) {
        a1v[j] = (short)(__float_as_uint((float)(1 + l + 2 * j)) >> 16);
        b1v[j] = (short)(__float_as_uint((float)(2 + 2 * l + 3 * j)) >> 16);
        a2v[j] = (short)(__float_as_uint((float)(5 - l + j)) >> 16);
        b2v[j] = (short)(__float_as_uint((float)(-3 + l - 2 * j)) >> 16);
    }
    f32x4 pacc;
#pragma unroll
    for (int r = 0; r < 4; ++r) pacc[r] = (float)(1000 * r + 17 * l);
    pacc = __builtin_amdgcn_mfma_f32_16x16x32_bf16(a1v, b1v, pacc, 0, 0, 0);
    pacc = __builtin_amdgcn_mfma_f32_16x16x32_bf16(a2v, b2v, pacc, 0, 0, 0);
    unsigned int my = 0;
    for (int combo = 0; combo < 8; ++combo) {
        const int ai = combo >> 2, bi = (combo >> 1) & 1, dd = combo & 1;
        bool ok = true;
        for (int r = 0; r < 4; ++r) {
            int mm = dd ? (l & 15) : (4 * (l >> 4) + r);
            int nn = dd ? (4 * (l >> 4) + r) : (l & 15);
            double e = 1000.0 * r + 17.0 * l;
            for (int k = 0; k < 32; ++k) {
                int lA = ai ? (4 * mm + (k >> 3)) : (mm + 16 * (k >> 3));
                int lB = bi ? (4 * nn + (k >> 3)) : (nn + 16 * (k >> 3));
                int jj = k & 7;
                e += (double)((1 + lA + 2 * jj) * (2 + 2 * lB + 3 * jj)
                            + (5 - lA + jj) * (-3 + lB - 2 * jj));
            }
            ok = ok && ((double)pacc[r] == e);
        }
        if (ok) my |= 1u << combo;
    }
    atomicAnd(&maskls, my);
    __syncthreads();
    if (l == 0) out[0] = maskls ? (unsigned)(__ffs((int)maskls) - 1) : 255u;
}

// bf16x3-split GEMM: ci = X @ Win^T via 8 exact cross-products per K-32 on the
// bf16 MFMA pipe, fp32 accumulate smallest-first, drain to fp64 every K-32.
// Error ~2.6e-7 in ci — ~6x tighter than jax's fp32 GEMM, which produced zero
// spike flips vs numpy (threshold provenance). Zero flips -> output bit-equal.
// Tile 64x128, 4 waves (wave = 16 rows x 8 nt), 3 bf16 planes in LDS (45 KB).
__global__ __launch_bounds__(256, 3) void gemm_bf(const float* __restrict__ X,
        const float* __restrict__ Win, float* __restrict__ C,
        const unsigned int* __restrict__ bfp) {
    const unsigned int bm = bfp[0];
    if (bm >= 8u) return;
    __shared__ unsigned int Au[3][64 * 20];    // [plane][row*20] 40-bf16 stride
    __shared__ unsigned int Bu[3][128 * 20];
    const int tid = threadIdx.x;
    const int lane = tid & 63, wv = tid >> 6;
    const int a_m  = (bm & 4) ? (lane >> 2) : (lane & 15);
    const int a_kb = (bm & 4) ? (lane & 3)  : (lane >> 4);
    const int b_n  = (bm & 2) ? (lane >> 2) : (lane & 15);
    const int b_kb = (bm & 2) ? (lane & 3)  : (lane >> 4);
    const int di = (int)(bm & 1);
    const int row0 = blockIdx.y * 64, col0 = blockIdx.x * 128;
    const int sra = tid >> 2, ska = (tid & 3) * 8;    // A: 8 floats/thread
    const int srb = tid >> 1, skb = (tid & 1) * 16;   // B: 16 floats/thread

    double accd[8][4] = {};

    for (int kt = 0; kt < BKT; ++kt) {
        const int k0 = kt * 32;
        __syncthreads();   // previous iter's reads complete
        // ---- stage A (split into 3 planes) ----
        {
            unsigned short h1[8], h2[8], h3[8];
#pragma unroll
            for (int q = 0; q < 2; ++q) {
                int gk = k0 + ska + q * 4;
                float4 v = make_float4(0.f, 0.f, 0.f, 0.f);
                if (gk < INF)   // INF%4==0, gk%4==0 -> full float4 in-bounds
                    v = *(const float4*)(X + (size_t)(row0 + sra) * INF + gk);
                bsplit(v.x, h1[q*4+0], h2[q*4+0], h3[q*4+0]);
                bsplit(v.y, h1[q*4+1], h2[q*4+1], h3[q*4+1]);
                bsplit(v.z, h1[q*4+2], h2[q*4+2], h3[q*4+2]);
                bsplit(v.w, h1[q*4+3], h2[q*4+3], h3[q*4+3]);
            }
            const int ab = sra * 20 + (ska >> 1);
#pragma unroll
            for (int e = 0; e < 2; ++e) {
                uint2 p;
                p.x = (unsigned)h1[e*4+0] | ((unsigned)h1[e*4+1] << 16);
                p.y = (unsigned)h1[e*4+2] | ((unsigned)h1[e*4+3] << 16);
                *(uint2*)&Au[0][ab + e*2] = p;
                p.x = (unsigned)h2[e*4+0] | ((unsigned)h2[e*4+1] << 16);
                p.y = (unsigned)h2[e*4+2] | ((unsigned)h2[e*4+3] << 16);
                *(uint2*)&Au[1][ab + e*2] = p;
                p.x = (unsigned)h3[e*4+0] | ((unsigned)h3[e*4+1] << 16);
                p.y = (unsigned)h3[e*4+2] | ((unsigned)h3[e*4+3] << 16);
                *(uint2*)&Au[2][ab + e*2] = p;
            }
        }
        // ---- stage B ----
        {
            unsigned short g1[16], g2[16], g3[16];
#pragma unroll
            for (int q = 0; q < 4; ++q) {
                int gk = k0 + skb + q * 4;
                float4 v = make_float4(0.f, 0.f, 0.f, 0.f);
                if (gk < INF)
                    v = *(const float4*)(Win + (size_t)(col0 + srb) * INF + gk);
                bsplit(v.x, g1[q*4+0], g2[q*4+0], g3[q*4+0]);
                bsplit(v.y, g1[q*4+1], g2[q*4+1], g3[q*4+1]);
                bsplit(v.z, g1[q*4+2], g2[q*4+2], g3[q*4+2]);
                bsplit(v.w, g1[q*4+3], g2[q*4+3], g3[q*4+3]);
            }
            const int bb = srb * 20 + (skb >> 1);
#pragma unroll
            for (int e = 0; e < 4; ++e) {
                uint2 p;
                p.x = (unsigned)g1[e*4+0] | ((unsigned)g1[e*4+1] << 16);
                p.y = (unsigned)g1[e*4+2] | ((unsigned)g1[e*4+3] << 16);
                *(uint2*)&Bu[0][bb + e*2] = p;
                p.x = (unsigned)g2[e*4+0] | ((unsigned)g2[e*4+1] << 16);
                p.y = (unsigned)g2[e*4+2] | ((unsigned)g2[e*4+3] << 16);
                *(uint2*)&Bu[1][bb + e*2] = p;
                p.x = (unsigned)g3[e*4+0] | ((unsigned)g3[e*4+1] << 16);
                p.y = (unsigned)g3[e*4+2] | ((unsigned)g3[e*4+3] << 16);
                *(uint2*)&Bu[2][bb + e*2] = p;
            }
        }
        __syncthreads();
        // ---- fragments + 8 exact cross-product MFMAs per nt, fp64 drain ----
        const int ar = (wv * 16 + a_m) * 20 + a_kb * 4;
        short8 fa1 = *(short8*)&Au[0][ar];
        short8 fa2 = *(short8*)&Au[1][ar];
        short8 fa3 = *(short8*)&Au[2][ar];
#pragma unroll
        for (int nt = 0; nt < 8; ++nt) {
            const int br = (nt * 16 + b_n) * 20 + b_kb * 4;
            short8 fb1 = *(short8*)&Bu[0][br];
            short8 fb2 = *(short8*)&Bu[1][br];
            short8 fb3 = *(short8*)&Bu[2][br];
            f32x4 acc = {0.f, 0.f, 0.f, 0.f};
            acc = __builtin_amdgcn_mfma_f32_16x16x32_bf16(fa3, fb2, acc, 0, 0, 0);
            acc = __builtin_amdgcn_mfma_f32_16x16x32_bf16(fa2, fb3, acc, 0, 0, 0);
            acc = __builtin_amdgcn_mfma_f32_16x16x32_bf16(fa3, fb1, acc, 0, 0, 0);
            acc = __builtin_amdgcn_mfma_f32_16x16x32_bf16(fa2, fb2, acc, 0, 0, 0);
            acc = __builtin_amdgcn_mfma_f32_16x16x32_bf16(fa1, fb3, acc, 0, 0, 0);
            acc = __builtin_amdgcn_mfma_f32_16x16x32_bf16(fa2, fb1, acc, 0, 0, 0);
            acc = __builtin_amdgcn_mfma_f32_16x16x32_bf16(fa1, fb2, acc, 0, 0, 0);
            acc = __builtin_amdgcn_mfma_f32_16x16x32_bf16(fa1, fb1, acc, 0, 0, 0);
            accd[nt][0] += (double)acc[0]; accd[nt][1] += (double)acc[1];
            accd[nt][2] += (double)acc[2]; accd[nt][3] += (double)acc[3];
        }
    }
#pragma unroll
    for (int nt = 0; nt < 8; ++nt)
#pragma unroll
        for (int r = 0; r < 4; ++r) {
            int m = di ? (lane & 15) : (4 * (lane >> 4) + r);
            int n = di ? (4 * (lane >> 4) + r) : (lane & 15);
            C[(size_t)(row0 + wv * 16 + m) * HIDN + col0 + nt * 16 + n]
                = (float)accd[nt][r];
        }
}

// f64 MFMA fallback: VERBATIM R16 gemm_mfma3. Runs only if bf16 probe failed.
__global__ __launch_bounds__(256, 3) void gemm_mfma3(const float* __restrict__ X,
        const float* __restrict__ Win, float* __restrict__ C,
        const unsigned int* __restrict__ modep, const unsigned int* __restrict__ bfp) {
    if (bfp[0] < 8u) return;
    const unsigned int mode = modep[0];
    if (mode >= 24u) return;
    const int di = (int)(mode % 6u), bi = (int)((mode / 6u) & 1u), ai = (int)(mode / 12u);
    __shared__ float As[32][72];
    __shared__ float Bs[32][144];
    const int tid = threadIdx.x;
    const int lane = tid & 63, wv = tid >> 6;
    const int a_m = ai ? (lane >> 2) : (lane & 15);
    const int a_k = ai ? (lane & 3) : (lane >> 4);
    const int b_n = bi ? (lane >> 2) : (lane & 15);
    const int b_k = bi ? (lane & 3) : (lane >> 4);
    const int row0 = blockIdx.y * 64, col0 = blockIdx.x * 128;
    const int sra = tid >> 2, ska = (tid & 3) * 8;
    const int srb = tid >> 1, skb = (tid & 1) * 16;

    float4 va[2], vb[4];
#pragma unroll
    for (int q = 0; q < 2; ++q)
        va[q] = *(const float4*)(X + (size_t)(row0 + sra) * INF + ska + q * 4);
#pragma unroll
    for (int q = 0; q < 4; ++q)
        vb[q] = *(const float4*)(Win + (size_t)(col0 + srb) * INF + skb + q * 4);

    f64x4 acc[8] = {};
    for (int k0 = 0; k0 < INF; k0 += 32) {
        __syncthreads();
#pragma unroll
        for (int q = 0; q < 2; ++q) {
            int kc = ska + q * 4;
            As[kc + 0][sra] = va[q].x; As[kc + 1][sra] = va[q].y;
            As[kc + 2][sra] = va[q].z; As[kc + 3][sra] = va[q].w;
        }
#pragma unroll
        for (int q = 0; q < 4; ++q) {
            int kc = skb + q * 4;
            Bs[kc + 0][srb] = vb[q].x; Bs[kc + 1][srb] = vb[q].y;
            Bs[kc + 2][srb] = vb[q].z; Bs[kc + 3][srb] = vb[q].w;
        }
        __syncthreads();
        const int kn = k0 + 32;
        if (kn < INF) {
#pragma unroll
            for (int q = 0; q < 2; ++q) {
                int gk = kn + ska + q * 4;
                float4 a = make_float4(0.f, 0.f, 0.f, 0.f);
                if (gk < INF)
                    a = *(const float4*)(X + (size_t)(row0 + sra) * INF + gk);
                va[q] = a;
            }
#pragma unroll
            for (int q = 0; q < 4; ++q) {
                int gk = kn + skb + q * 4;
                float4 b = make_float4(0.f, 0.f, 0.f, 0.f);
                if (gk < INF)
                    b = *(const float4*)(Win + (size_t)(col0 + srb) * INF + gk);
                vb[q] = b;
            }
        }
#pragma unroll
        for (int s = 0; s < 8; ++s) {
            double a = (double)As[s * 4 + a_k][wv * 16 + a_m];
#pragma unroll
            for (int nt = 0; nt < 8; ++nt) {
                double b = (double)Bs[s * 4 + b_k][nt * 16 + b_n];
                acc[nt] = __builtin_amdgcn_mfma_f64_16x16x4f64(a, b, acc[nt], 0, 0, 0);
            }
        }
    }
#pragma unroll
    for (int nt = 0; nt < 8; ++nt)
#pragma unroll
        for (int r = 0; r < 4; ++r) {
            int m, n; dpos_f64(di, lane, r, m, n);
            C[(size_t)(row0 + wv * 16 + m) * HIDN + col0 + nt * 16 + n]
                = (float)acc[nt][r];
        }
}

// Vector fallback (frozen chain, VERBATIM R10). Runs only if BOTH probes fail.
__global__ __launch_bounds__(256, 2) void gemm_vec(const float* __restrict__ X,
        const float* __restrict__ Win, float* __restrict__ C,
        const unsigned int* __restrict__ modep, const unsigned int* __restrict__ bfp) {
    if (bfp[0] < 8u || modep[0] < 24u) return;
    __shared__ double As[32][130];
    __shared__ double Bs[32][144];
    const int tid = threadIdx.x;
    const int tx = tid & 15;
    const int ty = tid >> 4;
    const int row0 = blockIdx.y * 128, col0 = blockIdx.x * 128;
    const int sr = tid >> 1, sk = (tid & 1) * 16;
    const int srz = sr + (sr >> 3);
    float4 va[4], vb[4];
#pragma unroll
    for (int q = 0; q < 4; ++q) {
        int gk = sk + q * 4;
        va[q] = *(const float4*)(X + (size_t)(row0 + sr) * INF + gk);
        vb[q] = *(const float4*)(Win + (size_t)(col0 + sr) * INF + gk);
    }
    double acc[8][8] = {};
    for (int k0 = 0; k0 < INF; k0 += 32) {
        __syncthreads();
#pragma unroll
        for (int q = 0; q < 4; ++q) {
            int kc = sk + q * 4;
            As[kc + 0][sr] = (double)va[q].x; As[kc + 1][sr] = (double)va[q].y;
            As[kc + 2][sr] = (double)va[q].z; As[kc + 3][sr] = (double)va[q].w;
            Bs[kc + 0][srz] = (double)vb[q].x; Bs[kc + 1][srz] = (double)vb[q].y;
            Bs[kc + 2][srz] = (double)vb[q].z; Bs[kc + 3][srz] = (double)vb[q].w;
        }
        __syncthreads();
        const int kn = k0 + 32;
        if (kn < INF) {
#pragma unroll
            for (int q = 0; q < 4; ++q) {
                int gk = kn + sk + q * 4;
                float4 a = make_float4(0.f, 0.f, 0.f, 0.f);
                float4 b = make_float4(0.f, 0.f, 0.f, 0.f);
                if (gk < INF) {
                    a = *(const float4*)(X + (size_t)(row0 + sr) * INF + gk);
                    b = *(const float4*)(Win + (size_t)(col0 + sr) * INF + gk);
                }
                va[q] = a; vb[q] = b;
            }
        }
#pragma unroll 4
        for (int kk = 0; kk < 32; ++kk) {
            double ad[8], bd[8];
#pragma unroll
            for (int i = 0; i < 8; ++i) ad[i] = As[kk][ty * 8 + i];
#pragma unroll
            for (int j = 0; j < 8; ++j) bd[j] = Bs[kk][9 * tx + j];
#pragma unroll
            for (int i = 0; i < 8; ++i)
#pragma unroll
                for (int j = 0; j < 8; ++j)
                    acc[i][j] += ad[i] * bd[j];
        }
    }
#pragma unroll
    for (int i = 0; i < 8; ++i) {
#pragma unroll
        for (int jj = 0; jj < 2; ++jj) {
            float4 o;
            o.x = (float)acc[i][jj * 4 + 0]; o.y = (float)acc[i][jj * 4 + 1];
            o.z = (float)acc[i][jj * 4 + 2]; o.w = (float)acc[i][jj * 4 + 3];
            *(float4*)(C + (size_t)(row0 + ty * 8 + i) * HIDN + col0 + tx * 8 + jj * 4) = o;
        }
    }
}

// Fused stepper with TAG-EMBEDDED z exchange. VERBATIM R19/R20 (~250us).
__global__ __launch_bounds__(512) void fused_tag(const float* __restrict__ ci,
        const float* __restrict__ wT, const float* __restrict__ w_out,
        float* __restrict__ out, unsigned char* __restrict__ zb) {
    __shared__ float zfb[4096];        // 16 KB union: zf[b][j] | fbufT[c2][b][h]
    __shared__ float wout2[2][512];    // 4 KB
    const int tid = threadIdx.x;
    const int wv = tid >> 6, lane = tid & 63;
    const int i = (int)blockIdx.x;
    const int c = (i >> 3) & 7;                    // h-chunk / group member
    const int g = (i & 7) | ((i >> 6) << 3);       // group 0..31 (co-XCD)
    const int b0 = g * 8;

    float wreg[64];
#pragma unroll
    for (int qq = 0; qq < 64; ++qq)
        wreg[qq] = wT[(size_t)((wv << 6) + qq) * HIDN + (c << 6) + lane];

    if (tid < 512) {
        wout2[0][tid] = w_out[c * HIDN + tid];
        wout2[1][tid] = (c < 2) ? w_out[(8 + c) * HIDN + tid] : 0.0f;
    }
    for (int idx = tid; idx < 4096; idx += 512) zfb[idx] = 0.0f;  // z_{-1}=0
    __syncthreads();

    unsigned char* zbA = zb + (size_t)b0 * HIDN;            // [b][j] u8
    unsigned char* zbB = zb + 131072 + (size_t)b0 * HIDN;

    float pos = 0.0f;                  // fold phase: thread = (batch wv, h lane)
    float vA = 0.f, iA = 0.f, vB = 0.f, iB = 0.f;   // LI state on lane 0

    for (int t = 0; t < TSTEPS; ++t) {
        float f[8] = {0.f, 0.f, 0.f, 0.f, 0.f, 0.f, 0.f, 0.f};
#pragma unroll
        for (int q4 = 0; q4 < 16; ++q4) {
            float4 z4[8];
#pragma unroll
            for (int b = 0; b < 8; ++b)
                z4[b] = *(const float4*)&zfb[b * 512 + (wv << 6) + q4 * 4];
#pragma unroll
            for (int b = 0; b < 8; ++b) {
                f[b] = __fmaf_rn(z4[b].x, wreg[q4 * 4 + 0], f[b]);
                f[b] = __fmaf_rn(z4[b].y, wreg[q4 * 4 + 1], f[b]);
                f[b] = __fmaf_rn(z4[b].z, wreg[q4 * 4 + 2], f[b]);
                f[b] = __fmaf_rn(z4[b].w, wreg[q4 * 4 + 3], f[b]);
            }
        }
        __syncthreads();   // B1: all zf reads done; region becomes fbufT
#pragma unroll
        for (int b = 0; b < 8; ++b)
            zfb[((wv << 3) + b) * 64 + lane] = f[b];   // fbufT[c2=wv][b][h]
        __syncthreads();   // B2: partials published

        double acc = 0.0;
#pragma unroll
        for (int c2 = 0; c2 < 8; ++c2)
            acc += (double)zfb[((c2 << 3) + wv) * 64 + lane];
        float rec32 = (float)acc;
        float civ = ci[((size_t)t * NB + (b0 + wv)) * HIDN + (c << 6) + lane];
        float cur = __fadd_rn(__fadd_rn(civ, rec32), 1e-4f);   // (in+rec)+I_APP
        float mc = __fmul_rn(2.5e5f, cur);                     // MU*cur
        pos = __fadd_rn(pos, __fmul_rn(1e-10f, mc));           // pos += DT*(..)
        bool zbit = __fsub_rn(pos, 2.5e-8f) > 0.0f;            // pos-W2 > 0
        pos = zbit ? 0.0f : pos;
        unsigned char* zw = (t & 1) ? zbB : zbA;
        const unsigned int tag2 = ((unsigned)(t >> 1) + 1u) << 1;   // <=101
        __hip_atomic_store(&zw[wv * HIDN + (c << 6) + lane],
                           (unsigned char)(tag2 | (zbit ? 1u : 0u)),
                           __ATOMIC_RELAXED, __HIP_MEMORY_SCOPE_AGENT);
        __syncthreads();   // B3: fbufT reads done -> zfb reusable as zf

        {
            const int bb = tid >> 6, j8 = (tid & 63) * 8;
            const unsigned char* zr = zw + bb * HIDN + j8;
            const unsigned int t2b = tag2 * 0x01010101u;
            unsigned int vx, vy;
            for (;;) {
                vx = __hip_atomic_load((const unsigned int*)zr,
                                       __ATOMIC_RELAXED, __HIP_MEMORY_SCOPE_AGENT);
                vy = __hip_atomic_load((const unsigned int*)(zr + 4),
                                       __ATOMIC_RELAXED, __HIP_MEMORY_SCOPE_AGENT);
                if (((vx & 0xFEFEFEFEu) == t2b) && ((vy & 0xFEFEFEFEu) == t2b))
                    break;
                __builtin_amdgcn_s_sleep(1);
            }
            float4 o0, o1;
            o0.x = (float)(vx & 1u);         o0.y = (float)((vx >> 8) & 1u);
            o0.z = (float)((vx >> 16) & 1u); o0.w = (float)((vx >> 24) & 1u);
            o1.x = (float)(vy & 1u);         o1.y = (float)((vy >> 8) & 1u);
            o1.z = (float)((vy >> 16) & 1u); o1.w = (float)((vy >> 24) & 1u);
            *(float4*)&zfb[bb * 512 + j8] = o0;
            *(float4*)&zfb[bb * 512 + j8 + 4] = o1;
        }
        __syncthreads();   // B4: zf ready for LI + next gather

#pragma unroll
        for (int oo = 0; oo < 2; ++oo) {
            int o = (oo == 0) ? c : (c < 2 ? 8 + c : -1);
            if (o < 0) continue;
            double part = 0.0;
#pragma unroll
            for (int c2 = 0; c2 < 8; ++c2) {
                double zfv = (double)zfb[wv * 512 + (c2 << 6) + lane];
                part = __fma_rn(zfv, (double)wout2[oo][(c2 << 6) + lane], part);
            }
#pragma unroll
            for (int off = 32; off > 0; off >>= 1) part += __shfl_down(part, off);
            if (lane == 0) {
                float inp = (float)part;
                float vvv = (oo == 0) ? vA : vB;
                float iiv = (oo == 0) ? iA : iB;
                float vn = __fadd_rn(vvv, __fmul_rn(1e-8f, __fsub_rn(iiv, vvv)));
                float t2 = __fmul_rn(2e-8f, iiv);
                float in2 = __fadd_rn(__fsub_rn(iiv, t2), inp);
                if (oo == 0) { vA = vn; iA = in2; } else { vB = vn; iB = in2; }
                out[((size_t)t * NB + (b0 + wv)) * NOUT + o] = vn;
            }
        }
    }
}

extern "C" void kernel_launch(void* const* d_in, const int* in_sizes, int n_in,
                              void* d_out, int out_size, void* d_ws, size_t ws_size,
                              hipStream_t stream) {
    (void)in_sizes; (void)n_in; (void)out_size;
    const float* x     = (const float*)d_in[0];
    const float* w_in  = (const float*)d_in[1];
    const float* w_rec = (const float*)d_in[2];
    const float* w_out = (const float*)d_in[3];
    float* out = (float*)d_out;
    float* ws  = (float*)d_ws;
    if (ws_size < (size_t)WS_FLOATS * 4) return;

    float* wT = ws + OFF_WT;
    unsigned char* zb = (unsigned char*)(ws + OFF_ZB);
    unsigned int* ctr = (unsigned int*)(ws + OFF_CTR);
    unsigned int* bfmode = ctr + 1022;
    unsigned int* mode = ctr + 1023;
    float* ci = ws + OFF_CI;

    hipLaunchKernelGGL(init_kernel, dim3((OFF_CI + 255) / 256), dim3(256), 0,
                       stream, ws, w_rec);
    hipLaunchKernelGGL(probe_kernel, dim3(1), dim3(64), 0, stream, mode);
    hipLaunchKernelGGL(probe_bf, dim3(1), dim3(64), 0, stream, bfmode);
    hipLaunchKernelGGL(gemm_bf, dim3(4, 400), dim3(256), 0, stream,
                       x, w_in, ci, bfmode);
    hipLaunchKernelGGL(gemm_mfma3, dim3(4, 400), dim3(256), 0, stream,
                       x, w_in, ci, mode, bfmode);
    hipLaunchKernelGGL(gemm_vec, dim3(4, 200), dim3(256), 0, stream,
                       x, w_in, ci, mode, bfmode);
    hipLaunchKernelGGL(fused_tag, dim3(NB), dim3(512), 0, stream,
                       ci, wT, w_out, out, zb);
}